// Round 1
// baseline (438.660 us; speedup 1.0000x reference)
//
#include <hip/hip_runtime.h>

// PillarFeatureNet: linear(9->64, no bias) -> BN1d over (B*Cout, P*N=64) cols
// -> ReLU -> max over N. Stats via Gram-matrix trick (no x materialization).
//
// ws layout (floats):
//   [0, 3456)      : S[j][54] accumulators, j = p*2+n in [0,64), 54 = 9 (S1) + 45 (S2 triangle)
//   [3456, 3520)   : a[j]   (scale)
//   [3520, 3584)   : bb[j]  (shift)

#define CIN 9
#define NPAIR 45
#define SREC 54
#define EPS_BN 1e-5f
#define WS_AB 3456

__global__ __launch_bounds__(256) void pfn_stats(const float* __restrict__ pillars,
                                                 float* __restrict__ ws, int B) {
    __shared__ float red[256][SREC];
    const int tid = threadIdx.x;
    const int lane = tid & 63;          // j = p*2+n
    const int gw = blockIdx.x * 4 + (tid >> 6);
    const int nw = gridDim.x * 4;

    float s1[CIN];
    float s2[NPAIR];
#pragma unroll
    for (int c = 0; c < CIN; ++c) s1[c] = 0.f;
#pragma unroll
    for (int k = 0; k < NPAIR; ++k) s2[k] = 0.f;

    for (int b = gw; b < B; b += nw) {
        const float* p = pillars + (size_t)b * 576 + lane * 9;
        float v[CIN];
#pragma unroll
        for (int c = 0; c < CIN; ++c) v[c] = p[c];
#pragma unroll
        for (int c = 0; c < CIN; ++c) s1[c] += v[c];
        int k = 0;
#pragma unroll
        for (int c = 0; c < CIN; ++c)
#pragma unroll
            for (int c2 = c; c2 < CIN; ++c2) { s2[k] += v[c] * v[c2]; ++k; }
    }

#pragma unroll
    for (int c = 0; c < CIN; ++c) red[tid][c] = s1[c];
#pragma unroll
    for (int k = 0; k < NPAIR; ++k) red[tid][9 + k] = s2[k];
    __syncthreads();

    if (tid < 64) {
        for (int k = 0; k < SREC; ++k) {
            float s = red[tid][k] + red[tid + 64][k] + red[tid + 128][k] + red[tid + 192][k];
            atomicAdd(&ws[tid * SREC + k], s);
        }
    }
}

__global__ __launch_bounds__(64) void pfn_finalize(const float* __restrict__ W,
                                                   const float* __restrict__ gamma,
                                                   const float* __restrict__ beta,
                                                   float* __restrict__ ws, float invBC) {
    const int j = threadIdx.x;  // 0..63
    float wrow[CIN];
#pragma unroll
    for (int c = 0; c < CIN; ++c) wrow[c] = W[j * CIN + c];

    float wsum[CIN];
    float G[NPAIR];
#pragma unroll
    for (int c = 0; c < CIN; ++c) wsum[c] = wrow[c];
    {
        int k = 0;
#pragma unroll
        for (int c = 0; c < CIN; ++c)
#pragma unroll
            for (int c2 = c; c2 < CIN; ++c2) { G[k] = wrow[c] * wrow[c2]; ++k; }
    }
    // butterfly wave reduction over 64 lanes (all lanes end with totals)
#pragma unroll
    for (int off = 32; off >= 1; off >>= 1) {
#pragma unroll
        for (int c = 0; c < CIN; ++c) wsum[c] += __shfl_xor(wsum[c], off);
#pragma unroll
        for (int k = 0; k < NPAIR; ++k) G[k] += __shfl_xor(G[k], off);
    }

    const float* S = ws + j * SREC;
    float mean = 0.f;
#pragma unroll
    for (int c = 0; c < CIN; ++c) mean = fmaf(wsum[c], S[c], mean);
    mean *= invBC;

    float e2 = 0.f;
    {
        int k = 0;
#pragma unroll
        for (int c = 0; c < CIN; ++c)
#pragma unroll
            for (int c2 = c; c2 < CIN; ++c2) {
                e2 = fmaf(G[k] * (c == c2 ? 1.f : 2.f), S[9 + k], e2);
                ++k;
            }
    }
    e2 *= invBC;

    const float var = e2 - mean * mean;
    const float a = rsqrtf(var + EPS_BN) * gamma[j];
    const float bb = beta[j] - mean * a;
    ws[WS_AB + j] = a;
    ws[WS_AB + 64 + j] = bb;
}

__global__ __launch_bounds__(256) void pfn_main(const float* __restrict__ pillars,
                                                const float* __restrict__ W,
                                                const float* __restrict__ ws,
                                                float* __restrict__ out, int B) {
    const int tid = threadIdx.x;
    const int lane = tid & 63;     // j = p*2+n
    const int p = lane >> 1;
    const int n = lane & 1;
    const float a = ws[WS_AB + lane];
    const float bb = ws[WS_AB + 64 + lane];

    const int gw = blockIdx.x * 4 + (tid >> 6);
    const int nw = gridDim.x * 4;

    for (int b = gw; b < B; b += nw) {
        const float* Pb = pillars + (size_t)b * 576 + lane * 9;
        float P[CIN];
#pragma unroll
        for (int c = 0; c < CIN; ++c) P[c] = Pb[c];

        float* Ob = out + (size_t)b * 2048;  // [o][p], p fastest
#pragma unroll 4
        for (int t = 0; t < 32; ++t) {
            const float* w0 = W + (2 * t) * CIN;   // uniform address -> s_load
            float x0 = 0.f, x1 = 0.f;
#pragma unroll
            for (int c = 0; c < CIN; ++c) {
                x0 = fmaf(P[c], w0[c], x0);
                x1 = fmaf(P[c], w0[CIN + c], x1);
            }
            float v0 = fmaxf(fmaf(x0, a, bb), 0.f);
            float v1 = fmaxf(fmaf(x1, a, bb), 0.f);
            // max over n: partner lane differs only in n bit
            const float m0 = fmaxf(v0, __shfl_xor(v0, 1));
            const float m1 = fmaxf(v1, __shfl_xor(v1, 1));
            // lane (p,n) stores: o = 2t+n, addr = (2t+n)*32 + p  (256B/wave, coalesced)
            Ob[t * 64 + n * 32 + p] = n ? m1 : m0;
        }
    }
}

extern "C" void kernel_launch(void* const* d_in, const int* in_sizes, int n_in,
                              void* d_out, int out_size, void* d_ws, size_t ws_size,
                              hipStream_t stream) {
    const float* pillars = (const float*)d_in[0];
    // d_in[1] = num_points_per_pillar: unused by the reference computation
    const float* W = (const float*)d_in[2];
    const float* gamma = (const float*)d_in[3];
    const float* beta = (const float*)d_in[4];
    float* out = (float*)d_out;
    float* ws = (float*)d_ws;

    const int B = in_sizes[0] / 576;  // 16384

    // zero the stats accumulators (ws is poisoned before every launch)
    hipMemsetAsync(ws, 0, 3456 * sizeof(float), stream);
    pfn_stats<<<512, 256, 0, stream>>>(pillars, ws, B);
    pfn_finalize<<<1, 64, 0, stream>>>(W, gamma, beta, ws, 1.0f / ((float)B * 64.0f));
    pfn_main<<<1024, 256, 0, stream>>>(pillars, W, ws, out, B);
}

// Round 2
// 187.634 us; speedup vs baseline: 2.3378x; 2.3378x over previous
//
#include <hip/hip_runtime.h>

// PillarFeatureNet: linear(9->64, no bias) -> BN1d (training stats over B*Cout
// rows, P*N=64 cols) -> ReLU -> max over N.
//
// Stats via Gram trick: mean[j] = invBC * sum_b dot(wsum, v[b,j])
//                       E[x^2][j] = invBC * sum_b v^T G v,  G = W^T W (9x9 full)
// All local arrays constant-indexed; no variable-bound loops (round-1 spill fix).
//
// ws float layout:
//   [0,81)      G (9x9 row-major)
//   [81,90)     wsum
//   [96,1120)   8 shadow copies x 128 accumulator floats
//               copy s, feature j, t(0=acc1,1=acc2): 96 + s*128 + j*2 + t
//   [1120,1184) a[j]   (BN scale)
//   [1184,1248) bb[j]  (BN shift)

#define EPS_BN 1e-5f

__global__ __launch_bounds__(64) void pfn_prep(const float* __restrict__ W,
                                               float* __restrict__ ws) {
    __shared__ float prod[64][90];
    const int o = threadIdx.x;  // 0..63
    float w[9];
#pragma unroll
    for (int c = 0; c < 9; ++c) w[c] = W[o * 9 + c];
#pragma unroll
    for (int c = 0; c < 9; ++c)
#pragma unroll
        for (int c2 = 0; c2 < 9; ++c2) prod[o][c * 9 + c2] = w[c] * w[c2];
#pragma unroll
    for (int c = 0; c < 9; ++c) prod[o][81 + c] = w[c];
    // zero the 8 shadow accumulator copies: 1024 floats
#pragma unroll
    for (int k = 0; k < 16; ++k) ws[96 + o * 16 + k] = 0.f;
    __syncthreads();
    for (int col = o; col < 90; col += 64) {
        float s = 0.f;
        for (int r = 0; r < 64; ++r) s += prod[r][col];
        ws[col] = s;
    }
}

__global__ __launch_bounds__(256) void pfn_stats(const float* __restrict__ pillars,
                                                 const float* __restrict__ gw,
                                                 float* __restrict__ acc8,
                                                 int npairs) {
    const int tid = threadIdx.x;
    const int lane = tid & 63;
    const int p = lane & 31;
    const int bsub = lane >> 5;

    // wave-uniform: expect s_load / SGPR residency (separate __restrict__ ptr,
    // never written by this kernel)
    float G[81], wsum[9];
#pragma unroll
    for (int k = 0; k < 81; ++k) G[k] = gw[k];
#pragma unroll
    for (int c = 0; c < 9; ++c) wsum[c] = gw[81 + c];

    float a1_0 = 0.f, a2_0 = 0.f;  // j0 = 2p  (n=0)
    float a1_1 = 0.f, a2_1 = 0.f;  // j1 = 2p+1 (n=1)

    const int wid = blockIdx.x * 4 + (tid >> 6);
    const int nw = gridDim.x * 4;
    for (int pr = wid; pr < npairs; pr += nw) {
        const float2* src =
            (const float2*)(pillars + (size_t)(pr * 2 + bsub) * 576 + p * 18);
        float v[18];
#pragma unroll
        for (int k = 0; k < 9; ++k) {
            const float2 t = src[k];
            v[2 * k] = t.x;
            v[2 * k + 1] = t.y;
        }
        float d0 = 0.f, d1 = 0.f, q0 = 0.f, q1 = 0.f;
#pragma unroll
        for (int c = 0; c < 9; ++c) {
            d0 = fmaf(wsum[c], v[c], d0);
            d1 = fmaf(wsum[c], v[9 + c], d1);
            float t0 = 0.f, t1 = 0.f;
#pragma unroll
            for (int c2 = 0; c2 < 9; ++c2) {
                const float g = G[c * 9 + c2];
                t0 = fmaf(g, v[c2], t0);
                t1 = fmaf(g, v[9 + c2], t1);
            }
            q0 = fmaf(v[c], t0, q0);
            q1 = fmaf(v[9 + c], t1, q1);
        }
        a1_0 += d0; a2_0 += q0;
        a1_1 += d1; a2_1 += q1;
    }

    __shared__ float red[256][5];  // padded: stride 5 kills bank aliasing
    red[tid][0] = a1_0; red[tid][1] = a2_0;
    red[tid][2] = a1_1; red[tid][3] = a2_1;
    __syncthreads();
    if (tid < 32) {  // thread tid handles p = tid (rows tid + 32k, k<8)
        float s0 = 0.f, s1 = 0.f, s2 = 0.f, s3 = 0.f;
#pragma unroll
        for (int k = 0; k < 8; ++k) {
            s0 += red[tid + 32 * k][0];
            s1 += red[tid + 32 * k][1];
            s2 += red[tid + 32 * k][2];
            s3 += red[tid + 32 * k][3];
        }
        float* acc = acc8 + (blockIdx.x & 7) * 128;
        atomicAdd(&acc[(2 * tid) * 2], s0);
        atomicAdd(&acc[(2 * tid) * 2 + 1], s1);
        atomicAdd(&acc[(2 * tid + 1) * 2], s2);
        atomicAdd(&acc[(2 * tid + 1) * 2 + 1], s3);
    }
}

__global__ __launch_bounds__(64) void pfn_finalize(const float* __restrict__ gamma,
                                                   const float* __restrict__ beta,
                                                   float* __restrict__ ws,
                                                   float invBC) {
    const int j = threadIdx.x;  // 0..63
    float s1 = 0.f, s2 = 0.f;
#pragma unroll
    for (int s = 0; s < 8; ++s) {
        s1 += ws[96 + s * 128 + j * 2];
        s2 += ws[96 + s * 128 + j * 2 + 1];
    }
    const float mean = s1 * invBC;
    const float var = s2 * invBC - mean * mean;
    const float a = rsqrtf(var + EPS_BN) * gamma[j];
    const float bb = beta[j] - mean * a;
    ws[1120 + j] = a;
    ws[1184 + j] = bb;
}

__global__ __launch_bounds__(256) void pfn_main(const float* __restrict__ pillars,
                                                const float* __restrict__ W,
                                                const float* __restrict__ ws,
                                                float* __restrict__ out,
                                                int npairs) {
    __shared__ float smW[64 * 12];  // W rows padded to 12 -> 16B-aligned rows
    const int tid = threadIdx.x;
    for (int i = tid; i < 576; i += 256) smW[(i / 9) * 12 + (i % 9)] = W[i];

    const int lane = tid & 63;
    const int p = lane & 31;
    const int bsub = lane >> 5;
    const float a0 = ws[1120 + 2 * p], a1 = ws[1120 + 2 * p + 1];
    const float b0 = ws[1184 + 2 * p], b1 = ws[1184 + 2 * p + 1];
    __syncthreads();

    const int pr = blockIdx.x * 4 + (tid >> 6);
    if (pr >= npairs) return;
    const int b = pr * 2 + bsub;

    float v[18];
    const float2* src = (const float2*)(pillars + (size_t)b * 576 + p * 18);
#pragma unroll
    for (int k = 0; k < 9; ++k) {
        const float2 t = src[k];
        v[2 * k] = t.x;
        v[2 * k + 1] = t.y;
    }

    float* Ob = out + (size_t)b * 2048 + p;
#pragma unroll 4
    for (int o = 0; o < 64; ++o) {
        float x0 = 0.f, x1 = 0.f;
#pragma unroll
        for (int c = 0; c < 9; ++c) {
            const float w = smW[o * 12 + c];
            x0 = fmaf(w, v[c], x0);
            x1 = fmaf(w, v[9 + c], x1);
        }
        const float r0 = fmaxf(fmaf(x0, a0, b0), 0.f);
        const float r1 = fmaxf(fmaf(x1, a1, b1), 0.f);
        Ob[o * 32] = fmaxf(r0, r1);  // lanes 0-31 -> b, 32-63 -> b+1: 2x128B segs
    }
}

extern "C" void kernel_launch(void* const* d_in, const int* in_sizes, int n_in,
                              void* d_out, int out_size, void* d_ws, size_t ws_size,
                              hipStream_t stream) {
    const float* pillars = (const float*)d_in[0];
    // d_in[1] = num_points_per_pillar: unused by the reference computation
    const float* W = (const float*)d_in[2];
    const float* gamma = (const float*)d_in[3];
    const float* beta = (const float*)d_in[4];
    float* out = (float*)d_out;
    float* ws = (float*)d_ws;

    const int B = in_sizes[0] / 576;  // 16384
    const int npairs = B / 2;

    pfn_prep<<<1, 64, 0, stream>>>(W, ws);
    pfn_stats<<<1024, 256, 0, stream>>>(pillars, ws, ws + 96, npairs);
    pfn_finalize<<<1, 64, 0, stream>>>(gamma, beta, ws, 1.0f / ((float)B * 64.0f));
    pfn_main<<<2048, 256, 0, stream>>>(pillars, W, ws, out, npairs);
}